// Round 1
// baseline (15228.876 us; speedup 1.0000x reference)
//
#include <hip/hip_runtime.h>
#include <cstddef>

// ---------------------------------------------------------------------------
// RelGraphConv GNN, 10 layers. Round 0: f32 correctness baseline.
// N=100000, E=600000, F=64, H=128, R=8.
// Pipeline per layer:
//   msg = x @ W_loop[l] + b_rel[l]                (GEMM, initializes accumulator)
//   for r in 0..7: xr = x @ W_rel[l][r]; msg[dst] += xr[src] (atomic scatter)
//   mid = tanh([x|msg] @ W_u1[l] + b_u1[l])
//   x'  = tanh([x|mid] @ W_u2[l] + b_u2[l])
// Edges bucketed by etype once per launch (etype is layer-invariant).
// Workspace: xA(51.2M) + msg(51.2M) + mid(102.4M) + xr(51.2M) + edge idx ≈ 261 MB
// ---------------------------------------------------------------------------

#define FEAT 64
#define HID 128
#define NREL 8
#define NL 10

__global__ __launch_bounds__(256) void k_zero_ints(int* p, int n) {
  int i = blockIdx.x * 256 + threadIdx.x;
  if (i < n) p[i] = 0;
}

__global__ __launch_bounds__(256) void k_hist(const int* __restrict__ et,
                                              int* __restrict__ cnt, int E) {
  int e = blockIdx.x * 256 + threadIdx.x;
  if (e < E) atomicAdd(&cnt[et[e]], 1);
}

__global__ void k_scan8(const int* __restrict__ cnt, int* __restrict__ off,
                        int* __restrict__ cur) {
  if (threadIdx.x == 0) {
    int a = 0;
    for (int r = 0; r < NREL; r++) { off[r] = a; cur[r] = a; a += cnt[r]; }
    off[NREL] = a;
  }
}

__global__ __launch_bounds__(256) void k_bucket(const int* __restrict__ et,
                                                const int* __restrict__ src,
                                                const int* __restrict__ dst,
                                                int* cur,
                                                int* __restrict__ es,
                                                int* __restrict__ ed, int E) {
  int e = blockIdx.x * 256 + threadIdx.x;
  if (e < E) {
    int p = atomicAdd(&cur[et[e]], 1);
    es[p] = src[e];
    ed[p] = dst[e];
  }
}

// msg[dst] += xr[src], one relation bucket, grid-stride, 128 threads/edge.
__global__ __launch_bounds__(256) void k_scatter(const int* __restrict__ off,
                                                 const int* __restrict__ cnt,
                                                 const int* __restrict__ es,
                                                 const int* __restrict__ ed,
                                                 const float* __restrict__ xr,
                                                 float* __restrict__ msg, int r) {
  int n = cnt[r];
  int base = off[r];
  int lane = threadIdx.x & (HID - 1);
  int slot = threadIdx.x >> 7;  // 2 edges per 256-thread block per iter
  for (int e = blockIdx.x * 2 + slot; e < n; e += gridDim.x * 2) {
    int s = es[base + e], d = ed[base + e];
    unsafeAtomicAdd(&msg[(size_t)d * HID + lane], xr[(size_t)s * HID + lane]);
  }
}

// ---------------------------------------------------------------------------
// Generic f32 GEMM: C = act(concat(A0, A1) @ B + bias)
// A0: [M, K0], A1: [M, K-K0] (null if K0 == K), B: [K, Nc] row-major.
// Tile: 64 rows x 128 cols, BK = 32, 256 threads, 4x8 outputs/thread.
// As stored transposed [k][m] padded to 68 (16B-aligned rows, 2-way banks).
// act: 0 = identity, 1 = tanh
// ---------------------------------------------------------------------------
__global__ __launch_bounds__(256) void gemm_f32(
    const float* __restrict__ A0, const float* __restrict__ A1, int K0, int K,
    const float* __restrict__ B, const float* __restrict__ bias,
    float* __restrict__ C, int M, int Nc, int act) {
  __shared__ float As[32][68];
  __shared__ float Bs[32][128];
  const int tid = threadIdx.x;
  const int m0 = blockIdx.x * 64;
  const int bn0 = blockIdx.y * 128;
  const int tm = tid & 15;   // row group: rows tm*4 .. tm*4+3
  const int tn = tid >> 4;   // col group: cols tn*4..+3 and 64+tn*4..+3

  float acc[4][8];
#pragma unroll
  for (int i = 0; i < 4; i++)
#pragma unroll
    for (int j = 0; j < 8; j++) acc[i][j] = 0.f;

  const int KA1 = K - K0;  // A1 row stride

  for (int k0 = 0; k0 < K; k0 += 32) {
    // --- stage A tile [64 rows x 32 k] transposed into As[k][m] ---
#pragma unroll
    for (int i = 0; i < 2; i++) {
      int idx = tid + i * 256;       // 0..511
      int row = idx >> 3;            // 0..63
      int kg = idx & 7;              // 0..7 (float4 groups)
      int gr = m0 + row;
      int gk = k0 + kg * 4;
      float4 v = make_float4(0.f, 0.f, 0.f, 0.f);
      if (gr < M) {
        if (gk < K0)
          v = *(const float4*)(&A0[(size_t)gr * K0 + gk]);
        else
          v = *(const float4*)(&A1[(size_t)gr * KA1 + (gk - K0)]);
      }
      As[kg * 4 + 0][row] = v.x;
      As[kg * 4 + 1][row] = v.y;
      As[kg * 4 + 2][row] = v.z;
      As[kg * 4 + 3][row] = v.w;
    }
    // --- stage B tile [32 k x 128 cols] ---
#pragma unroll
    for (int i = 0; i < 4; i++) {
      int idx = tid + i * 256;       // 0..1023
      int row = idx >> 5;            // 0..31
      int cg = idx & 31;             // 0..31
      float4 v = *(const float4*)(&B[(size_t)(k0 + row) * Nc + bn0 + cg * 4]);
      *(float4*)(&Bs[row][cg * 4]) = v;
    }
    __syncthreads();

#pragma unroll 8
    for (int kk = 0; kk < 32; kk++) {
      float4 a = *(const float4*)(&As[kk][tm * 4]);
      float4 b0 = *(const float4*)(&Bs[kk][tn * 4]);
      float4 b1 = *(const float4*)(&Bs[kk][64 + tn * 4]);
      float av[4] = {a.x, a.y, a.z, a.w};
      float bv[8] = {b0.x, b0.y, b0.z, b0.w, b1.x, b1.y, b1.z, b1.w};
#pragma unroll
      for (int i = 0; i < 4; i++)
#pragma unroll
        for (int j = 0; j < 8; j++) acc[i][j] += av[i] * bv[j];
    }
    __syncthreads();
  }

  // --- epilogue: bias + activation, float4 stores ---
#pragma unroll
  for (int i = 0; i < 4; i++) {
    int gr = m0 + tm * 4 + i;
    if (gr >= M) continue;
#pragma unroll
    for (int h = 0; h < 2; h++) {
      int c = bn0 + h * 64 + tn * 4;
      float4 o;
      o.x = acc[i][h * 4 + 0];
      o.y = acc[i][h * 4 + 1];
      o.z = acc[i][h * 4 + 2];
      o.w = acc[i][h * 4 + 3];
      if (bias) {
        o.x += bias[c + 0]; o.y += bias[c + 1];
        o.z += bias[c + 2]; o.w += bias[c + 3];
      }
      if (act) {
        o.x = tanhf(o.x); o.y = tanhf(o.y);
        o.z = tanhf(o.z); o.w = tanhf(o.w);
      }
      *(float4*)(&C[(size_t)gr * Nc + c]) = o;
    }
  }
}

extern "C" void kernel_launch(void* const* d_in, const int* in_sizes, int n_in,
                              void* d_out, int out_size, void* d_ws, size_t ws_size,
                              hipStream_t stream) {
  const float* feats  = (const float*)d_in[0];
  const int*   src    = (const int*)d_in[1];
  const int*   dst    = (const int*)d_in[2];
  const int*   etype  = (const int*)d_in[3];
  const float* W_in   = (const float*)d_in[4];
  const float* b_in   = (const float*)d_in[5];
  const float* W_rel  = (const float*)d_in[6];
  const float* W_loop = (const float*)d_in[7];
  const float* b_rel  = (const float*)d_in[8];
  const float* W_u1   = (const float*)d_in[9];
  const float* b_u1   = (const float*)d_in[10];
  const float* W_u2   = (const float*)d_in[11];
  const float* b_u2   = (const float*)d_in[12];

  const int E = in_sizes[1];
  const int N = in_sizes[0] / FEAT;

  // workspace layout (floats)
  float* xA  = (float*)d_ws;                  // N*H
  float* msg = xA + (size_t)N * HID;          // N*H
  float* mid = msg + (size_t)N * HID;         // N*2H
  float* xr  = mid + (size_t)N * 2 * HID;     // N*H
  int* es_src = (int*)(xr + (size_t)N * HID); // E
  int* es_dst = es_src + E;                   // E
  int* cnt = es_dst + E;                      // 8
  int* off = cnt + NREL;                      // 9
  int* cur = off + NREL + 1;                  // 8
  float* xO = (float*)d_out;

  // --- bucket edges by etype (once per launch; etype layer-invariant) ---
  k_zero_ints<<<1, 32, 0, stream>>>(cnt, NREL + (NREL + 1) + NREL);
  k_hist<<<(E + 255) / 256, 256, 0, stream>>>(etype, cnt, E);
  k_scan8<<<1, 64, 0, stream>>>(cnt, off, cur);
  k_bucket<<<(E + 255) / 256, 256, 0, stream>>>(etype, src, dst, cur, es_src, es_dst, E);

  const dim3 blk(256);
  const dim3 g1((N + 63) / 64, 1);
  const dim3 g2((N + 63) / 64, 2);

  // input projection -> d_out (ping-pong start so layer 9 ends in d_out)
  gemm_f32<<<g1, blk, 0, stream>>>(feats, nullptr, FEAT, FEAT, W_in, b_in, xO, N, HID, 1);

  for (int l = 0; l < NL; l++) {
    const float* xin = (l & 1) ? xA : xO;
    float* xout = (l & 1) ? xO : xA;

    // msg = xin @ W_loop[l] + b_rel[l]  (initializes scatter accumulator)
    gemm_f32<<<g1, blk, 0, stream>>>(xin, nullptr, HID, HID,
                                     W_loop + (size_t)l * HID * HID,
                                     b_rel + (size_t)l * HID, msg, N, HID, 0);

    for (int r = 0; r < NREL; r++) {
      gemm_f32<<<g1, blk, 0, stream>>>(xin, nullptr, HID, HID,
                                       W_rel + ((size_t)(l * NREL + r)) * HID * HID,
                                       nullptr, xr, N, HID, 0);
      k_scatter<<<2048, blk, 0, stream>>>(off, cnt, es_src, es_dst, xr, msg, r);
    }

    // mid = tanh([x | msg] @ W_u1[l] + b_u1[l])
    gemm_f32<<<g2, blk, 0, stream>>>(xin, msg, HID, 2 * HID,
                                     W_u1 + (size_t)l * 2 * HID * 2 * HID,
                                     b_u1 + (size_t)l * 2 * HID, mid, N, 2 * HID, 1);

    // x' = tanh([x | mid] @ W_u2[l] + b_u2[l])
    gemm_f32<<<g1, blk, 0, stream>>>(xin, mid, HID, 3 * HID,
                                     W_u2 + (size_t)l * 3 * HID * HID,
                                     b_u2 + (size_t)l * HID, xout, N, HID, 1);
  }
}

// Round 2
// 7811.028 us; speedup vs baseline: 1.9497x; 1.9497x over previous
//
#include <hip/hip_runtime.h>
#include <cstddef>

// ---------------------------------------------------------------------------
// RelGraphConv GNN, 10 layers. Round 2: bf16 MFMA GEMMs + bucketing removed.
// N=100000, E=600000, F=64, H=128, R=8, layers=10.
//
// Per launch:
//   - transpose+convert all weights f32[K][N] -> bf16[N][K] (MFMA B-operand
//     wants [n][k] with k contiguous, same as A's [m][k])
//   - convert feats to bf16
//   - x = tanh(feats @ W_in + b_in)
//   - per layer: msg=f32(x@W_loop+b); 4x {xr=x@[W_rel 2r|2r+1] (f32);
//     scatter msg[dst]+=xr[src]}; mid=tanh([x|msg]@W_u1+b); x'=tanh([x|mid]@W_u2+b)
// msg stays f32 (atomic accumulator); xr stays f32 (feeds atomics directly);
// everything entering MFMA is bf16 (rounded at staging).
// Workspace ~223 MB: xb0/xb1 (bf16 25.6M ea) + msg (f32 51.2M) +
// xr (f32 102.4M, aliased by mid bf16) + featsb (12.8M) + weights bf16 (5.3M)
// ---------------------------------------------------------------------------

#define HID 128
#define NREL 8
#define NL 10

typedef __attribute__((ext_vector_type(8))) __bf16 bf16x8;
typedef __attribute__((ext_vector_type(4))) float f32x4;

// --- batched transpose + f32->bf16: W[z][K][Nc] -> Wt[z][Nc][K] ---
// K, Nc multiples of 32. block (32,8).
__global__ __launch_bounds__(256) void k_transpose(const float* __restrict__ W,
                                                   __bf16* __restrict__ Wt,
                                                   int K, int Nc) {
  __shared__ float t[32][33];
  const float* Wz = W + (size_t)blockIdx.z * K * Nc;
  __bf16* Wtz = Wt + (size_t)blockIdx.z * K * Nc;
  int n0 = blockIdx.x * 32, k0 = blockIdx.y * 32;
#pragma unroll
  for (int i = 0; i < 4; i++) {
    int k = k0 + threadIdx.y + i * 8;
    int n = n0 + threadIdx.x;
    t[threadIdx.y + i * 8][threadIdx.x] = Wz[(size_t)k * Nc + n];
  }
  __syncthreads();
#pragma unroll
  for (int i = 0; i < 4; i++) {
    int n = n0 + threadIdx.y + i * 8;
    int k = k0 + threadIdx.x;
    Wtz[(size_t)n * K + k] = (__bf16)t[threadIdx.x][threadIdx.y + i * 8];
  }
}

// --- f32 -> bf16 elementwise (n4 = count/4) ---
__global__ __launch_bounds__(256) void k_cvt(const float* __restrict__ x,
                                             __bf16* __restrict__ y, int n4) {
  int i = blockIdx.x * 256 + threadIdx.x;
  if (i < n4) {
    float4 f = ((const float4*)x)[i];
    __bf16 o[4] = {(__bf16)f.x, (__bf16)f.y, (__bf16)f.z, (__bf16)f.w};
    *(uint2*)(y + (size_t)i * 4) = *(uint2*)o;
  }
}

// --- scatter: msg[dst] += xr[src, rl*128 + h] for edges with etype>>1 == rb ---
// 128 threads/edge (2 waves), 2 edges per 256-block per iter; wave-uniform edge.
__global__ __launch_bounds__(256) void k_scatter(const int* __restrict__ etype,
                                                 const int* __restrict__ src,
                                                 const int* __restrict__ dst,
                                                 const float* __restrict__ xr,
                                                 float* __restrict__ msg,
                                                 int rb, int E) {
  int lane = threadIdx.x & 127;
  int slot = threadIdx.x >> 7;
  for (int e = blockIdx.x * 2 + slot; e < E; e += gridDim.x * 2) {
    int r = etype[e];
    if ((r >> 1) != rb) continue;
    int s = src[e], d = dst[e];
    float v = xr[(size_t)s * 256 + (size_t)(r & 1) * 128 + lane];
    unsafeAtomicAdd(&msg[(size_t)d * 128 + lane], v);
  }
}

// ---------------------------------------------------------------------------
// bf16 MFMA GEMM: C[M x Nc] = act(concat(A0,A1)[M x K] @ B[K x Nc] + bias)
// Bt is the transposed bf16 weight [Nc][K]. A1 may be f32 (converted on stage)
// or bf16. Tile 128x128, BK=64, 256 thr = 4 waves in 2x2, each wave 64x64 via
// 4x4 grid of 16x16x32 MFMA tiles. LDS [spatial][k] padded to 72 (2-way banks).
// Outputs: Cb (bf16) and/or Cf (f32), either may be null. act: 1 = tanh.
// ---------------------------------------------------------------------------
__global__ __launch_bounds__(256) void gemm_bf16(
    const __bf16* __restrict__ A0, const void* __restrict__ A1v, int a1_f32,
    int K0, int K,
    const __bf16* __restrict__ Bt, const float* __restrict__ bias,
    __bf16* __restrict__ Cb, float* __restrict__ Cf,
    int M, int Nc, int act) {
  __shared__ __bf16 As[128][72];
  __shared__ __bf16 Bs[128][72];
  const int tid = threadIdx.x;
  const int m0 = blockIdx.x * 128;
  const int bn0 = blockIdx.y * 128;
  const int lane = tid & 63;
  const int w = tid >> 6;
  const int ml = lane & 15, q = lane >> 4;
  const int wr = (w >> 1) * 64, wc = (w & 1) * 64;
  const int KA1 = K - K0;

  f32x4 acc[4][4];
#pragma unroll
  for (int i = 0; i < 4; i++)
#pragma unroll
    for (int j = 0; j < 4; j++)
#pragma unroll
      for (int r = 0; r < 4; r++) acc[i][j][r] = 0.f;

  for (int k0 = 0; k0 < K; k0 += 64) {
    // stage A[128 x 64] and Bt[128 x 64] (both [spatial][k], 16B chunks)
#pragma unroll
    for (int i = 0; i < 4; i++) {
      int ci = tid + i * 256;       // 0..1023
      int row = ci >> 3;            // 0..127
      int kc = ci & 7;              // 16B chunk within 64-k row
      int gk = k0 + kc * 8;
      int gr = m0 + row;
      bf16x8 va;
#pragma unroll
      for (int z = 0; z < 8; z++) va[z] = (__bf16)0.f;
      if (gr < M) {
        if (gk < K0) {
          va = *(const bf16x8*)(A0 + (size_t)gr * K0 + gk);
        } else if (!a1_f32) {
          va = *(const bf16x8*)((const __bf16*)A1v + (size_t)gr * KA1 + (gk - K0));
        } else {
          const float* p = (const float*)A1v + (size_t)gr * KA1 + (gk - K0);
          float4 f0 = *(const float4*)p;
          float4 f1 = *(const float4*)(p + 4);
          va[0] = (__bf16)f0.x; va[1] = (__bf16)f0.y;
          va[2] = (__bf16)f0.z; va[3] = (__bf16)f0.w;
          va[4] = (__bf16)f1.x; va[5] = (__bf16)f1.y;
          va[6] = (__bf16)f1.z; va[7] = (__bf16)f1.w;
        }
      }
      *(bf16x8*)(&As[row][kc * 8]) = va;
      bf16x8 vb = *(const bf16x8*)(Bt + (size_t)(bn0 + row) * K + gk);
      *(bf16x8*)(&Bs[row][kc * 8]) = vb;
    }
    __syncthreads();
#pragma unroll
    for (int kk = 0; kk < 2; kk++) {
      bf16x8 af[4], bfr[4];
#pragma unroll
      for (int i = 0; i < 4; i++)
        af[i] = *(const bf16x8*)(&As[wr + i * 16 + ml][kk * 32 + q * 8]);
#pragma unroll
      for (int j = 0; j < 4; j++)
        bfr[j] = *(const bf16x8*)(&Bs[wc + j * 16 + ml][kk * 32 + q * 8]);
#pragma unroll
      for (int i = 0; i < 4; i++)
#pragma unroll
        for (int j = 0; j < 4; j++)
          acc[i][j] = __builtin_amdgcn_mfma_f32_16x16x32_bf16(af[i], bfr[j],
                                                              acc[i][j], 0, 0, 0);
    }
    __syncthreads();
  }

  // epilogue: C/D layout col=lane&15, row=(lane>>4)*4+reg
#pragma unroll
  for (int i = 0; i < 4; i++) {
#pragma unroll
    for (int r = 0; r < 4; r++) {
      int grow = m0 + wr + i * 16 + q * 4 + r;
      if (grow >= M) continue;
#pragma unroll
      for (int j = 0; j < 4; j++) {
        int col = bn0 + wc + j * 16 + ml;
        float v = acc[i][j][r];
        if (bias) v += bias[col];
        if (act) v = tanhf(v);
        if (Cb) Cb[(size_t)grow * Nc + col] = (__bf16)v;
        if (Cf) Cf[(size_t)grow * Nc + col] = v;
      }
    }
  }
}

extern "C" void kernel_launch(void* const* d_in, const int* in_sizes, int n_in,
                              void* d_out, int out_size, void* d_ws, size_t ws_size,
                              hipStream_t stream) {
  const float* feats  = (const float*)d_in[0];
  const int*   src    = (const int*)d_in[1];
  const int*   dst    = (const int*)d_in[2];
  const int*   etype  = (const int*)d_in[3];
  const float* W_in   = (const float*)d_in[4];
  const float* b_in   = (const float*)d_in[5];
  const float* W_rel  = (const float*)d_in[6];
  const float* W_loop = (const float*)d_in[7];
  const float* b_rel  = (const float*)d_in[8];
  const float* W_u1   = (const float*)d_in[9];
  const float* b_u1   = (const float*)d_in[10];
  const float* W_u2   = (const float*)d_in[11];
  const float* b_u2   = (const float*)d_in[12];

  const int E = in_sizes[1];
  const int N = in_sizes[0] / 64;  // feats is [N, 64]

  // --- workspace layout ---
  __bf16* xb0 = (__bf16*)d_ws;                       // N*128 bf16
  __bf16* xb1 = xb0 + (size_t)N * HID;               // N*128 bf16
  float*  msg = (float*)(xb1 + (size_t)N * HID);     // N*128 f32
  float*  xr  = msg + (size_t)N * HID;               // N*256 f32
  __bf16* mid = (__bf16*)xr;                         // N*256 bf16 (alias, xr dead)
  __bf16* featsb = (__bf16*)(xr + (size_t)N * 256);  // N*64 bf16
  __bf16* wt_in   = featsb + (size_t)N * 64;         // [128][64]
  __bf16* wt_rel  = wt_in + 128 * 64;                // [80][128][128]
  __bf16* wt_loop = wt_rel + (size_t)80 * 128 * 128; // [10][128][128]
  __bf16* wt_u1   = wt_loop + (size_t)10 * 128 * 128;// [10][256][256]
  __bf16* wt_u2   = wt_u1 + (size_t)10 * 256 * 256;  // [10][128][384]

  // --- weight transpose+convert (per launch; inputs re-poisoned each call) ---
  k_transpose<<<dim3(4, 2, 1),  dim3(32, 8), 0, stream>>>(W_in,   wt_in,   64, 128);
  k_transpose<<<dim3(4, 4, 80), dim3(32, 8), 0, stream>>>(W_rel,  wt_rel,  128, 128);
  k_transpose<<<dim3(4, 4, 10), dim3(32, 8), 0, stream>>>(W_loop, wt_loop, 128, 128);
  k_transpose<<<dim3(8, 8, 10), dim3(32, 8), 0, stream>>>(W_u1,   wt_u1,   256, 256);
  k_transpose<<<dim3(4, 12, 10), dim3(32, 8), 0, stream>>>(W_u2,  wt_u2,   384, 128);
  k_cvt<<<(N * 64 / 4 + 255) / 256, 256, 0, stream>>>(feats, featsb, N * 64 / 4);

  const dim3 blk(256);
  const int gm = (N + 127) / 128;
  const dim3 g1(gm, 1), g2(gm, 2);

  // input projection: x0 = tanh(featsb @ W_in + b_in)
  gemm_bf16<<<g1, blk, 0, stream>>>(featsb, nullptr, 0, 64, 64, wt_in, b_in,
                                    xb0, nullptr, N, HID, 1);

  for (int l = 0; l < NL; l++) {
    const __bf16* xin = (l & 1) ? xb1 : xb0;
    __bf16* xout = (l & 1) ? xb0 : xb1;

    // msg = xin @ W_loop[l] + b_rel[l]   (f32, scatter accumulator init)
    gemm_bf16<<<g1, blk, 0, stream>>>(xin, nullptr, 0, HID, HID,
                                      wt_loop + (size_t)l * HID * HID,
                                      b_rel + (size_t)l * HID,
                                      nullptr, msg, N, HID, 0);

    // relation projections (2 at a time) + scatter
    for (int rb = 0; rb < 4; rb++) {
      gemm_bf16<<<g2, blk, 0, stream>>>(xin, nullptr, 0, HID, HID,
                                        wt_rel + (size_t)(l * NREL + rb * 2) * HID * HID,
                                        nullptr, nullptr, xr, N, 256, 0);
      k_scatter<<<4096, blk, 0, stream>>>(etype, src, dst, xr, msg, rb, E);
    }

    // mid = tanh([x | msg] @ W_u1[l] + b_u1[l])   (msg staged f32->bf16)
    gemm_bf16<<<g2, blk, 0, stream>>>(xin, msg, 1, HID, 256,
                                      wt_u1 + (size_t)l * 256 * 256,
                                      b_u1 + (size_t)l * 256,
                                      mid, nullptr, N, 256, 1);

    // x' = tanh([x | mid] @ W_u2[l] + b_u2[l]); final layer -> f32 d_out
    gemm_bf16<<<g1, blk, 0, stream>>>(xin, mid, 0, HID, 384,
                                      wt_u2 + (size_t)l * HID * 384,
                                      b_u2 + (size_t)l * HID,
                                      (l == NL - 1) ? nullptr : xout,
                                      (l == NL - 1) ? (float*)d_out : nullptr,
                                      N, HID, 1);
  }
}

// Round 4
// 4699.659 us; speedup vs baseline: 3.2404x; 1.6620x over previous
//
#include <hip/hip_runtime.h>
#include <cstddef>

// ---------------------------------------------------------------------------
// RelGraphConv GNN, 10 layers. Round 4: round-3 structure with the edge_gemm
// staging bug fixed (full K=128 tile: 2048 16B-chunks, not 1024 — the upper
// half of As/Bs was uninitialized LDS -> NaN).
// N=100000, E=600000, F=64, H=128, R=8.
// ---------------------------------------------------------------------------

#define HID 128
#define NREL 8
#define NL 10

typedef __attribute__((ext_vector_type(8))) __bf16 bf16x8;
typedef __attribute__((ext_vector_type(4))) float f32x4;

// --- batched transpose + f32->bf16: W[z][K][Nc] -> Wt[z][Nc][K] ---
__global__ __launch_bounds__(256) void k_transpose(const float* __restrict__ W,
                                                   __bf16* __restrict__ Wt,
                                                   int K, int Nc) {
  __shared__ float t[32][33];
  const float* Wz = W + (size_t)blockIdx.z * K * Nc;
  __bf16* Wtz = Wt + (size_t)blockIdx.z * K * Nc;
  int n0 = blockIdx.x * 32, k0 = blockIdx.y * 32;
#pragma unroll
  for (int i = 0; i < 4; i++) {
    int k = k0 + threadIdx.y + i * 8;
    int n = n0 + threadIdx.x;
    t[threadIdx.y + i * 8][threadIdx.x] = Wz[(size_t)k * Nc + n];
  }
  __syncthreads();
#pragma unroll
  for (int i = 0; i < 4; i++) {
    int n = n0 + threadIdx.y + i * 8;
    int k = k0 + threadIdx.x;
    Wtz[(size_t)n * K + k] = (__bf16)t[threadIdx.x][threadIdx.y + i * 8];
  }
}

// --- f32 -> bf16 elementwise (n4 = count/4) ---
__global__ __launch_bounds__(256) void k_cvt(const float* __restrict__ x,
                                             __bf16* __restrict__ y, int n4) {
  int i = blockIdx.x * 256 + threadIdx.x;
  if (i < n4) {
    float4 f = ((const float4*)x)[i];
    __bf16 o[4] = {(__bf16)f.x, (__bf16)f.y, (__bf16)f.z, (__bf16)f.w};
    *(uint2*)(y + (size_t)i * 4) = *(uint2*)o;
  }
}

// ============================ edge bucketing ================================
__global__ __launch_bounds__(256) void k_count(const int* __restrict__ et, int E,
                                               int* __restrict__ blockCnt) {
  __shared__ int c[NREL];
  if (threadIdx.x < NREL) c[threadIdx.x] = 0;
  __syncthreads();
  int lo = blockIdx.x * 512;
#pragma unroll
  for (int i = 0; i < 2; i++) {
    int idx = lo + i * 256 + threadIdx.x;
    if (idx < E) atomicAdd(&c[et[idx]], 1);
  }
  __syncthreads();
  if (threadIdx.x < NREL) blockCnt[blockIdx.x * NREL + threadIdx.x] = c[threadIdx.x];
}

__global__ __launch_bounds__(256) void k_scan(const int* __restrict__ blockCnt,
                                              int NB, int* __restrict__ blockBase,
                                              int* __restrict__ cnt_g,
                                              int* __restrict__ off_g) {
  __shared__ int part[NREL][32];
  __shared__ int tot[NREL];
  int r = threadIdx.x >> 5, c = threadIdx.x & 31;
  int chunk = (NB + 31) / 32;
  int b0 = c * chunk, b1 = min(NB, b0 + chunk);
  int s = 0;
  for (int b = b0; b < b1; b++) s += blockCnt[b * NREL + r];
  part[r][c] = s;
  __syncthreads();
  if (c == 0) {
    int a = 0;
    for (int i = 0; i < 32; i++) { int v = part[r][i]; part[r][i] = a; a += v; }
    tot[r] = a;
    cnt_g[r] = a;
  }
  __syncthreads();
  if (threadIdx.x == 0) {
    int a = 0;
    for (int i = 0; i < NREL; i++) { off_g[i] = a; a += tot[i]; }
    off_g[NREL] = a;
  }
  int run = part[r][c];
  for (int b = b0; b < b1; b++) {
    blockBase[b * NREL + r] = run;
    run += blockCnt[b * NREL + r];
  }
}

__global__ __launch_bounds__(256) void k_place(const int* __restrict__ et,
                                               const int* __restrict__ src,
                                               const int* __restrict__ dst,
                                               const int* __restrict__ blockBase,
                                               const int* __restrict__ off_g,
                                               int* __restrict__ es,
                                               int* __restrict__ ed, int E) {
  __shared__ int base[NREL];
  if (threadIdx.x < NREL)
    base[threadIdx.x] = off_g[threadIdx.x] + blockBase[blockIdx.x * NREL + threadIdx.x];
  __syncthreads();
  int lo = blockIdx.x * 512;
#pragma unroll
  for (int i = 0; i < 2; i++) {
    int idx = lo + i * 256 + threadIdx.x;
    if (idx < E) {
      int p = atomicAdd(&base[et[idx]], 1);
      es[p] = src[idx];
      ed[p] = dst[idx];
    }
  }
}

__global__ __launch_bounds__(256) void k_tiles(const int* __restrict__ cnt_g,
                                               const int* __restrict__ off_g,
                                               int* __restrict__ trel,
                                               int* __restrict__ tlo,
                                               int* __restrict__ tn, int maxt) {
  int cnt[NREL], ts[NREL + 1];
  ts[0] = 0;
#pragma unroll
  for (int i = 0; i < NREL; i++) {
    cnt[i] = cnt_g[i];
    ts[i + 1] = ts[i] + (cnt[i] + 127) / 128;
  }
  for (int t = blockIdx.x * 256 + threadIdx.x; t < maxt; t += gridDim.x * 256) {
    int r = -1;
#pragma unroll
    for (int i = 0; i < NREL; i++)
      if (t >= ts[i] && t < ts[i + 1]) r = i;
    if (r < 0) {
      trel[t] = 0; tlo[t] = 0; tn[t] = 0;
    } else {
      int ti = t - ts[r];
      trel[t] = r;
      tlo[t] = off_g[r] + ti * 128;
      tn[t] = min(128, cnt[r] - ti * 128);
    }
  }
}

// ============================ fused edge GEMM ===============================
// One block = one 128-edge tile of one relation. Gather x[src] into LDS,
// multiply by W_rel[l][r] (transposed [n][k]), atomic-add rows into msg[dst].
__global__ __launch_bounds__(256) void edge_gemm(
    const __bf16* __restrict__ x, const __bf16* __restrict__ wt_rel_l,
    const int* __restrict__ es, const int* __restrict__ ed,
    const int* __restrict__ trel, const int* __restrict__ tlo,
    const int* __restrict__ tn, float* __restrict__ msg) {
  int t = blockIdx.x;
  int n = tn[t];
  if (n == 0) return;
  int r = trel[t], lo = tlo[t];

  __shared__ __bf16 As[128][136];
  __shared__ __bf16 Bs[128][136];
  __shared__ int dstl[128];

  const int tid = threadIdx.x;
  if (tid < 128) dstl[tid] = (tid < n) ? ed[lo + tid] : -1;

  const __bf16* W = wt_rel_l + (size_t)r * HID * HID;
  // FULL K=128 staging: 128 rows x 16 chunks of 16B = 2048 chunks, 8 per thread
#pragma unroll
  for (int i = 0; i < 8; i++) {
    int ci = tid + i * 256;        // 0..2047
    int row = ci >> 4;             // 0..127
    int kc = ci & 15;              // 0..15 (16B chunks covering 128 elems)
    *(bf16x8*)(&Bs[row][kc * 8]) = *(const bf16x8*)(W + (size_t)row * HID + kc * 8);
    int s = (row < n) ? es[lo + row] : es[lo];
    *(bf16x8*)(&As[row][kc * 8]) = *(const bf16x8*)(x + (size_t)s * HID + kc * 8);
  }
  __syncthreads();

  const int lane = tid & 63;
  const int w = tid >> 6;
  const int ml = lane & 15, q = lane >> 4;
  const int wr = (w >> 1) * 64, wc = (w & 1) * 64;

  f32x4 acc[4][4];
#pragma unroll
  for (int i = 0; i < 4; i++)
#pragma unroll
    for (int j = 0; j < 4; j++)
#pragma unroll
      for (int z = 0; z < 4; z++) acc[i][j][z] = 0.f;

#pragma unroll
  for (int kk = 0; kk < 4; kk++) {
    bf16x8 af[4], bfr[4];
#pragma unroll
    for (int i = 0; i < 4; i++)
      af[i] = *(const bf16x8*)(&As[wr + i * 16 + ml][kk * 32 + q * 8]);
#pragma unroll
    for (int j = 0; j < 4; j++)
      bfr[j] = *(const bf16x8*)(&Bs[wc + j * 16 + ml][kk * 32 + q * 8]);
#pragma unroll
    for (int i = 0; i < 4; i++)
#pragma unroll
      for (int j = 0; j < 4; j++)
        acc[i][j] = __builtin_amdgcn_mfma_f32_16x16x32_bf16(af[i], bfr[j],
                                                            acc[i][j], 0, 0, 0);
  }

#pragma unroll
  for (int i = 0; i < 4; i++) {
#pragma unroll
    for (int z = 0; z < 4; z++) {
      int row = wr + i * 16 + q * 4 + z;
      int d = dstl[row];
      if (d < 0) continue;
      float* mrow = msg + (size_t)d * HID + wc;
#pragma unroll
      for (int j = 0; j < 4; j++)
        unsafeAtomicAdd(&mrow[j * 16 + ml], acc[i][j][z]);
    }
  }
}

// ---------------------------------------------------------------------------
// bf16 MFMA GEMM (dense): C = act(concat(A0,A1) @ B + bias)   [round-2 proven]
// ---------------------------------------------------------------------------
__global__ __launch_bounds__(256) void gemm_bf16(
    const __bf16* __restrict__ A0, const void* __restrict__ A1v, int a1_f32,
    int K0, int K,
    const __bf16* __restrict__ Bt, const float* __restrict__ bias,
    __bf16* __restrict__ Cb, float* __restrict__ Cf,
    int M, int Nc, int act) {
  __shared__ __bf16 As[128][72];
  __shared__ __bf16 Bs[128][72];
  const int tid = threadIdx.x;
  const int m0 = blockIdx.x * 128;
  const int bn0 = blockIdx.y * 128;
  const int lane = tid & 63;
  const int w = tid >> 6;
  const int ml = lane & 15, q = lane >> 4;
  const int wr = (w >> 1) * 64, wc = (w & 1) * 64;
  const int KA1 = K - K0;

  f32x4 acc[4][4];
#pragma unroll
  for (int i = 0; i < 4; i++)
#pragma unroll
    for (int j = 0; j < 4; j++)
#pragma unroll
      for (int r = 0; r < 4; r++) acc[i][j][r] = 0.f;

  for (int k0 = 0; k0 < K; k0 += 64) {
#pragma unroll
    for (int i = 0; i < 4; i++) {
      int ci = tid + i * 256;
      int row = ci >> 3;
      int kc = ci & 7;
      int gk = k0 + kc * 8;
      int gr = m0 + row;
      bf16x8 va;
#pragma unroll
      for (int z = 0; z < 8; z++) va[z] = (__bf16)0.f;
      if (gr < M) {
        if (gk < K0) {
          va = *(const bf16x8*)(A0 + (size_t)gr * K0 + gk);
        } else if (!a1_f32) {
          va = *(const bf16x8*)((const __bf16*)A1v + (size_t)gr * KA1 + (gk - K0));
        } else {
          const float* p = (const float*)A1v + (size_t)gr * KA1 + (gk - K0);
          float4 f0 = *(const float4*)p;
          float4 f1 = *(const float4*)(p + 4);
          va[0] = (__bf16)f0.x; va[1] = (__bf16)f0.y;
          va[2] = (__bf16)f0.z; va[3] = (__bf16)f0.w;
          va[4] = (__bf16)f1.x; va[5] = (__bf16)f1.y;
          va[6] = (__bf16)f1.z; va[7] = (__bf16)f1.w;
        }
      }
      *(bf16x8*)(&As[row][kc * 8]) = va;
      bf16x8 vb = *(const bf16x8*)(Bt + (size_t)(bn0 + row) * K + gk);
      *(bf16x8*)(&Bs[row][kc * 8]) = vb;
    }
    __syncthreads();
#pragma unroll
    for (int kk = 0; kk < 2; kk++) {
      bf16x8 af[4], bfr[4];
#pragma unroll
      for (int i = 0; i < 4; i++)
        af[i] = *(const bf16x8*)(&As[wr + i * 16 + ml][kk * 32 + q * 8]);
#pragma unroll
      for (int j = 0; j < 4; j++)
        bfr[j] = *(const bf16x8*)(&Bs[wc + j * 16 + ml][kk * 32 + q * 8]);
#pragma unroll
      for (int i = 0; i < 4; i++)
#pragma unroll
        for (int j = 0; j < 4; j++)
          acc[i][j] = __builtin_amdgcn_mfma_f32_16x16x32_bf16(af[i], bfr[j],
                                                              acc[i][j], 0, 0, 0);
    }
    __syncthreads();
  }

#pragma unroll
  for (int i = 0; i < 4; i++) {
#pragma unroll
    for (int r = 0; r < 4; r++) {
      int grow = m0 + wr + i * 16 + q * 4 + r;
      if (grow >= M) continue;
#pragma unroll
      for (int j = 0; j < 4; j++) {
        int col = bn0 + wc + j * 16 + ml;
        float v = acc[i][j][r];
        if (bias) v += bias[col];
        if (act) v = tanhf(v);
        if (Cb) Cb[(size_t)grow * Nc + col] = (__bf16)v;
        if (Cf) Cf[(size_t)grow * Nc + col] = v;
      }
    }
  }
}

extern "C" void kernel_launch(void* const* d_in, const int* in_sizes, int n_in,
                              void* d_out, int out_size, void* d_ws, size_t ws_size,
                              hipStream_t stream) {
  const float* feats  = (const float*)d_in[0];
  const int*   src    = (const int*)d_in[1];
  const int*   dst    = (const int*)d_in[2];
  const int*   etype  = (const int*)d_in[3];
  const float* W_in   = (const float*)d_in[4];
  const float* b_in   = (const float*)d_in[5];
  const float* W_rel  = (const float*)d_in[6];
  const float* W_loop = (const float*)d_in[7];
  const float* b_rel  = (const float*)d_in[8];
  const float* W_u1   = (const float*)d_in[9];
  const float* b_u1   = (const float*)d_in[10];
  const float* W_u2   = (const float*)d_in[11];
  const float* b_u2   = (const float*)d_in[12];

  const int E = in_sizes[1];
  const int N = in_sizes[0] / 64;
  const int NB = (E + 511) / 512;
  const int MAXT = (E + 127) / 128 + NREL;

  // --- workspace layout ---
  __bf16* xb0 = (__bf16*)d_ws;                        // N*128
  __bf16* xb1 = xb0 + (size_t)N * HID;                // N*128
  float*  msg = (float*)(xb1 + (size_t)N * HID);      // N*128 f32
  __bf16* mid = (__bf16*)(msg + (size_t)N * HID);     // N*256 bf16
  __bf16* featsb = mid + (size_t)N * 256;             // N*64
  __bf16* wt_in   = featsb + (size_t)N * 64;          // [128][64]
  __bf16* wt_rel  = wt_in + 128 * 64;                 // [80][128][128]
  __bf16* wt_loop = wt_rel + (size_t)80 * 128 * 128;  // [10][128][128]
  __bf16* wt_u1   = wt_loop + (size_t)10 * 128 * 128; // [10][256][256]
  __bf16* wt_u2   = wt_u1 + (size_t)10 * 256 * 256;   // [10][128][384]
  int* es = (int*)(wt_u2 + (size_t)10 * 128 * 384);   // E
  int* ed = es + E;                                   // E
  int* blockCnt  = ed + E;                            // NB*8
  int* blockBase = blockCnt + NB * NREL;              // NB*8
  int* cnt_g = blockBase + NB * NREL;                 // 8
  int* off_g = cnt_g + NREL;                          // 9
  int* trel = off_g + NREL + 1;                       // MAXT
  int* tlo  = trel + MAXT;                            // MAXT
  int* tn   = tlo + MAXT;                             // MAXT

  // --- weight transpose+convert + feats convert ---
  k_transpose<<<dim3(4, 2, 1),   dim3(32, 8), 0, stream>>>(W_in,   wt_in,   64, 128);
  k_transpose<<<dim3(4, 4, 80),  dim3(32, 8), 0, stream>>>(W_rel,  wt_rel,  128, 128);
  k_transpose<<<dim3(4, 4, 10),  dim3(32, 8), 0, stream>>>(W_loop, wt_loop, 128, 128);
  k_transpose<<<dim3(8, 8, 10),  dim3(32, 8), 0, stream>>>(W_u1,   wt_u1,   256, 256);
  k_transpose<<<dim3(4, 12, 10), dim3(32, 8), 0, stream>>>(W_u2,   wt_u2,   384, 128);
  k_cvt<<<(N * 64 / 4 + 255) / 256, 256, 0, stream>>>(feats, featsb, N * 64 / 4);

  // --- edge bucketing (once; etype layer-invariant) ---
  k_count<<<NB, 256, 0, stream>>>(etype, E, blockCnt);
  k_scan<<<1, 256, 0, stream>>>(blockCnt, NB, blockBase, cnt_g, off_g);
  k_place<<<NB, 256, 0, stream>>>(etype, src, dst, blockBase, off_g, es, ed, E);
  k_tiles<<<(MAXT + 255) / 256, 256, 0, stream>>>(cnt_g, off_g, trel, tlo, tn, MAXT);

  const dim3 blk(256);
  const int gm = (N + 127) / 128;
  const dim3 g1(gm, 1), g2(gm, 2);

  // input projection
  gemm_bf16<<<g1, blk, 0, stream>>>(featsb, nullptr, 0, 64, 64, wt_in, b_in,
                                    xb0, nullptr, N, HID, 1);

  for (int l = 0; l < NL; l++) {
    const __bf16* xin = (l & 1) ? xb1 : xb0;
    __bf16* xout = (l & 1) ? xb0 : xb1;

    // msg = xin @ W_loop[l] + b_rel[l]
    gemm_bf16<<<g1, blk, 0, stream>>>(xin, nullptr, 0, HID, HID,
                                      wt_loop + (size_t)l * HID * HID,
                                      b_rel + (size_t)l * HID,
                                      nullptr, msg, N, HID, 0);

    // fused gather-GEMM-scatter over all relations
    edge_gemm<<<MAXT, blk, 0, stream>>>(xin, wt_rel + (size_t)l * NREL * HID * HID,
                                        es, ed, trel, tlo, tn, msg);

    // mid = tanh([x | msg] @ W_u1[l] + b_u1[l])
    gemm_bf16<<<g2, blk, 0, stream>>>(xin, msg, 1, HID, 256,
                                      wt_u1 + (size_t)l * 256 * 256,
                                      b_u1 + (size_t)l * 256,
                                      mid, nullptr, N, 256, 1);

    // x' = tanh([x | mid] @ W_u2[l] + b_u2[l]); last layer -> f32 d_out
    gemm_bf16<<<g1, blk, 0, stream>>>(xin, mid, 0, HID, 384,
                                      wt_u2 + (size_t)l * HID * 384,
                                      b_u2 + (size_t)l * HID,
                                      (l == NL - 1) ? nullptr : xout,
                                      (l == NL - 1) ? (float*)d_out : nullptr,
                                      N, HID, 1);
  }
}